// Round 1
// baseline (448.923 us; speedup 1.0000x reference)
//
#include <hip/hip_runtime.h>
#include <hip/hip_bf16.h>

#define T_TOK   16384
#define HID     4096
#define NEXP    64
#define NTOPK   8
#define CAPACITY 2048
#define TE      (T_TOK * NEXP)      // 1048576
#define NBLK2   (T_TOK / 64)        // 256 routing blocks
#define BT      128                 // tokens per gemm block-tile
#define BK      32                  // K-tile
#define KS      8                   // K-splits
#define NTILE   ((HID / KS) / BK)   // 16 tiles per block
#define XP      (BT + 4)            // 132: pad -> stride%32==4, 16B-aligned rows
#define WP      (NEXP + 4)          // 68

// ---------------- K1: gate GEMM  lp[split][t][e] ------------------------------
// grid (T/128, 8), block 256 (4 waves -> 4 waves/SIMD at 4 blocks/CU).
// Thread: 8 tokens x 4 experts. Register-prefetch pipeline: loads for tile t+1
// are issued before compute of tile t, so the vmcnt wait at the LDS store of
// t+1 lands a full compute phase after issue (HBM latency hidden).
__global__ __launch_bounds__(256, 4) void gemm_k(const float* __restrict__ x,
                                                 const float* __restrict__ wg,
                                                 float* __restrict__ lp) {
    __shared__ float xs[BK][XP];    // [k][t]  16.9 KB
    __shared__ float wsh[BK][WP];   // [k][e]   8.7 KB
    const int tid = threadIdx.x;
    const int tx = tid & 15, ty = tid >> 4;     // expert quad / token oct
    const int t0 = blockIdx.x * BT;
    const int kbase = blockIdx.y * (HID / KS);  // klen = 512
    const int scol = tid & 7;                   // float4 column (k/4)
    const int srow = tid >> 3;                  // staging row 0..31

    const float* xp0 = x  + (size_t)(t0 + srow) * HID + kbase + scol * 4;
    const float* wp0 = wg + (size_t)srow        * HID + kbase + scol * 4;

    float4 xv[4], wv[2];
#pragma unroll
    for (int j = 0; j < 4; ++j) xv[j] = *(const float4*)(xp0 + (size_t)(32 * j) * HID);
#pragma unroll
    for (int j = 0; j < 2; ++j) wv[j] = *(const float4*)(wp0 + (size_t)(32 * j) * HID);

    float acc[8][4];
#pragma unroll
    for (int i = 0; i < 8; ++i)
#pragma unroll
        for (int j = 0; j < 4; ++j) acc[i][j] = 0.f;

    for (int tile = 0; tile < NTILE; ++tile) {
        __syncthreads();                        // prev compute done, LDS free
#pragma unroll
        for (int j = 0; j < 4; ++j) {           // waits vmcnt on loads issued
            xs[scol * 4 + 0][srow + 32 * j] = xv[j].x;   // a full tile ago
            xs[scol * 4 + 1][srow + 32 * j] = xv[j].y;
            xs[scol * 4 + 2][srow + 32 * j] = xv[j].z;
            xs[scol * 4 + 3][srow + 32 * j] = xv[j].w;
        }
#pragma unroll
        for (int j = 0; j < 2; ++j) {
            wsh[scol * 4 + 0][srow + 32 * j] = wv[j].x;
            wsh[scol * 4 + 1][srow + 32 * j] = wv[j].y;
            wsh[scol * 4 + 2][srow + 32 * j] = wv[j].z;
            wsh[scol * 4 + 3][srow + 32 * j] = wv[j].w;
        }
        __syncthreads();
        if (tile + 1 < NTILE) {                 // issue next tile BEFORE compute
            const int koff = (tile + 1) * BK;
#pragma unroll
            for (int j = 0; j < 4; ++j)
                xv[j] = *(const float4*)(xp0 + (size_t)(32 * j) * HID + koff);
#pragma unroll
            for (int j = 0; j < 2; ++j)
                wv[j] = *(const float4*)(wp0 + (size_t)(32 * j) * HID + koff);
        }
#pragma unroll 8
        for (int k = 0; k < BK; ++k) {
            float4 a0 = *(const float4*)(&xs[k][ty * 8]);       // 16-way bcast
            float4 a1 = *(const float4*)(&xs[k][ty * 8 + 4]);
            float4 b0 = *(const float4*)(&wsh[k][tx * 4]);      // 2-way max
            float ar[8] = {a0.x, a0.y, a0.z, a0.w, a1.x, a1.y, a1.z, a1.w};
            float br[4] = {b0.x, b0.y, b0.z, b0.w};
#pragma unroll
            for (int i = 0; i < 8; ++i)
#pragma unroll
                for (int j = 0; j < 4; ++j)
                    acc[i][j] = fmaf(ar[i], br[j], acc[i][j]);
        }
    }
    float* op = lp + (size_t)blockIdx.y * TE + (size_t)(t0 + ty * 8) * NEXP + tx * 4;
#pragma unroll
    for (int i = 0; i < 8; ++i)
        *(float4*)(op + (size_t)i * NEXP) =
            make_float4(acc[i][0], acc[i][1], acc[i][2], acc[i][3]);
}

// ---------------- K2: softmax + group-limited top-k routing -------------------
// grid T/64, block 1024 (16 waves x 4 tokens each). lane = expert.
__global__ __launch_bounds__(1024) void route_k(const float* __restrict__ lp,
                                                int* __restrict__ ws_idx,
                                                float* __restrict__ ws_prob,
                                                int* __restrict__ ws_rank,
                                                int* __restrict__ ws_hist,
                                                float* __restrict__ ws_gsum) {
    __shared__ unsigned char idx_lds[64][8];
    __shared__ float gsum_lds[16][64];
    const int tid = threadIdx.x, lane = tid & 63, w = tid >> 6;
    const int blk = blockIdx.x;

    float gacc = 0.f;
    for (int i = 0; i < 4; ++i) {
        const int tloc = w * 4 + i;
        const int t = blk * 64 + tloc;
        float lg = 0.f;
        for (int s = 0; s < KS; ++s)
            lg += lp[(size_t)s * TE + (size_t)t * NEXP + lane];
        // softmax over 64 experts
        float m = lg;
#pragma unroll
        for (int off = 32; off; off >>= 1) m = fmaxf(m, __shfl_xor(m, off));
        float p = expf(lg - m);
        float s = p;
#pragma unroll
        for (int off = 32; off; off >>= 1) s += __shfl_xor(s, off);
        float gate = p / s;
        // group scores (max over 8 lanes within group), then top-4 groups
        float gsc = gate;
#pragma unroll
        for (int off = 1; off < 8; off <<= 1) gsc = fmaxf(gsc, __shfl_xor(gsc, off));
        const int g = lane >> 3;
        int grank = 0;
#pragma unroll
        for (int gg = 0; gg < 8; ++gg) {
            float o = __shfl(gsc, gg * 8);
            grank += (o > gsc || (o == gsc && gg < g)) ? 1 : 0;
        }
        float gm = (grank < 4) ? gate : 0.f;
        gacc += gm;
        // top-8 over 64 lanes; ties toward lower lane (lax.top_k)
        unsigned long long key =
            ((unsigned long long)__float_as_uint(gm) << 32) | (unsigned long long)(63 - lane);
        float dsum = 0.f;
        int my_e = 0; float my_v = 0.f;
#pragma unroll
        for (int r = 0; r < NTOPK; ++r) {
            unsigned long long b = key;
#pragma unroll
            for (int off = 32; off; off >>= 1) {
                unsigned long long o = __shfl_xor(b, off);
                b = (o > b) ? o : b;
            }
            int be = 63 - (int)(b & 63ull);
            float bv = __uint_as_float((unsigned)(b >> 32));
            dsum += bv;
            if (lane == r) { my_e = be; my_v = bv; }
            if (lane == be) key = 0ull;
        }
        float denom = fmaxf(dsum, 1.1920929e-7f);
        if (lane < NTOPK) {
            ws_idx[(size_t)t * NTOPK + lane]  = my_e;
            ws_prob[(size_t)t * NTOPK + lane] = my_v / denom;
            idx_lds[tloc][lane] = (unsigned char)my_e;
        }
    }
    gsum_lds[w][lane] = gacc;
    __syncthreads();
    // rank + hist via ballot: wave w<8 handles slot w; lane = token
    if (w < NTOPK) {
        const unsigned long long ltmask = (1ull << lane) - 1ull;
        const int ev = idx_lds[lane][w];
        int rank = 0, hc = 0;
        for (int e0 = 0; e0 < NEXP; ++e0) {
            unsigned long long msk = __ballot(ev == e0);
            if (ev == e0) rank = __popcll(msk & ltmask);
            if (lane == e0) hc = __popcll(msk);
        }
        ws_rank[(size_t)(blk * 64 + lane) * NTOPK + w] = rank;
        ws_hist[(size_t)(w * NEXP + lane) * NBLK2 + blk] = hc;  // [bin][block]
    }
    if (tid < 64) {
        float sg = 0.f;
#pragma unroll
        for (int ww = 0; ww < 16; ++ww) sg += gsum_lds[ww][tid];
        ws_gsum[(size_t)blk * NEXP + tid] = sg;
    }
}

// ---------------- K3a: per-bin exclusive scan, 1 wave per bin -----------------
__global__ __launch_bounds__(512) void scan_k(const int* __restrict__ hist,
                                              int* __restrict__ offs,
                                              int* __restrict__ tot) {
    const int bin = blockIdx.x * 8 + (threadIdx.x >> 6);
    const int lane = threadIdx.x & 63;
    int4 v = ((const int4*)(hist + (size_t)bin * NBLK2))[lane];
    int s = v.x + v.y + v.z + v.w;
    int incl = s;
#pragma unroll
    for (int off = 1; off < 64; off <<= 1) {
        int n = __shfl_up(incl, off);
        if (lane >= off) incl += n;
    }
    int excl = incl - s;
    int4 o;
    o.x = excl; o.y = excl + v.x; o.z = o.y + v.y; o.w = o.z + v.z;
    ((int4*)(offs + (size_t)bin * NBLK2))[lane] = o;
    if (lane == 63) tot[bin] = incl;
}

// ---------------- K3b: slot bases + scalar outputs ----------------------------
__global__ __launch_bounds__(256) void finalize_k(const int* __restrict__ tot,
                                                  const float* __restrict__ gsum,
                                                  int* __restrict__ base,
                                                  float* __restrict__ out) {
    __shared__ int tl[512];
    __shared__ float gl[256];
    const int tid = threadIdx.x;
    for (int i = tid; i < 512; i += 256) tl[i] = tot[i];
    {
        const int e = tid & 63, q = tid >> 6;
        float p = 0.f;
        for (int b = q * 64; b < q * 64 + 64; ++b) p += gsum[(size_t)b * NEXP + e];
        gl[tid] = p;
    }
    __syncthreads();
    for (int i = tid; i < 512; i += 256) {
        const int k = i >> 6, e = i & 63;
        int b = 0;
        for (int kk = 0; kk < k; ++kk) b += tl[kk * NEXP + e];
        base[i] = b;
    }
    if (tid < 64) {
        int cnt = 0;
#pragma unroll
        for (int k = 0; k < NTOPK; ++k) cnt += tl[k * NEXP + tid];
        out[2 + 3 * TE + tid] = (float)cnt;          // exp_counts
        float sg = gl[tid] + gl[64 + tid] + gl[128 + tid] + gl[192 + tid];
        float lx = (float)cnt * sg;
        int vs = cnt < CAPACITY ? cnt : CAPACITY;
#pragma unroll
        for (int off = 32; off; off >>= 1) {
            lx += __shfl_xor(lx, off);
            vs += __shfl_xor(vs, off);
        }
        if (tid == 0) {
            out[0] = 64.0f * lx / 268435456.0f;      // E^2 * sum / T^2
            out[1] = (float)vs / 131072.0f;          // / (T*TOPK)
        }
    }
}

// ---------------- K4: dense [T,64] combine / priority / valid -----------------
__global__ __launch_bounds__(256) void output_k(const int* __restrict__ ws_idx,
                                                const float* __restrict__ ws_prob,
                                                const int* __restrict__ ws_rank,
                                                const int* __restrict__ offs,
                                                const int* __restrict__ base,
                                                float* __restrict__ out) {
    const int gid = blockIdx.x * 256 + threadIdx.x;   // 0..TE/4-1
    const int t = gid >> 4, e0 = (gid & 15) << 2;
    const int4* ip = (const int4*)(ws_idx + (size_t)t * NTOPK);
    int4 ia = ip[0], ib = ip[1];
    int i8[NTOPK] = {ia.x, ia.y, ia.z, ia.w, ib.x, ib.y, ib.z, ib.w};
    float cw[4] = {0.f, 0.f, 0.f, 0.f}, pr[4] = {0.f, 0.f, 0.f, 0.f},
          vm[4] = {0.f, 0.f, 0.f, 0.f};
#pragma unroll
    for (int j = 0; j < 4; ++j) {
        const int e = e0 + j;
        int found = -1;
#pragma unroll
        for (int k = 0; k < NTOPK; ++k) if (i8[k] == e) found = k;
        if (found >= 0) {
            const int bin = found * NEXP + e;
            int pos = base[bin] + offs[(size_t)bin * NBLK2 + (t >> 6)] +
                      ws_rank[(size_t)t * NTOPK + found];
            if (pos < CAPACITY) {
                cw[j] = ws_prob[(size_t)t * NTOPK + found];
                pr[j] = (float)pos;
                vm[j] = 1.f;
            }
        }
    }
    ((float4*)(out + 2))[gid]          = make_float4(cw[0], cw[1], cw[2], cw[3]);
    ((float4*)(out + 2 + TE))[gid]     = make_float4(pr[0], pr[1], pr[2], pr[3]);
    ((float4*)(out + 2 + 2 * TE))[gid] = make_float4(vm[0], vm[1], vm[2], vm[3]);
}

// ---------------- launch ------------------------------------------------------
extern "C" void kernel_launch(void* const* d_in, const int* in_sizes, int n_in,
                              void* d_out, int out_size, void* d_ws, size_t ws_size,
                              hipStream_t stream) {
    const float* x  = (const float*)d_in[0];   // [16384, 4096] fp32
    const float* wg = (const float*)d_in[1];   // [64, 4096] fp32
    float* out = (float*)d_out;
    char* ws = (char*)d_ws;

    const size_t lp_bytes = (size_t)KS * TE * 4;   // 32 MB

    float* lp   = (float*)(ws);
    char*  rest = ws + lp_bytes;
    int*   idxw = (int*)  (rest);               // 512 KB
    float* prob = (float*)(rest + 524288);      // 512 KB
    int*   rank = (int*)  (rest + 1048576);     // 512 KB
    int*   hist = (int*)  (rest + 1572864);     // 512 KB  [bin][block]
    int*   offs = (int*)  (rest + 2097152);     // 512 KB  [bin][block]
    float* gsum = (float*)(rest + 2621440);     // 64 KB
    int*   tot  = (int*)  (rest + 2686976);     // 2 KB
    int*   base = (int*)  (rest + 2691072);     // 2 KB

    dim3 g1(T_TOK / BT, KS);
    gemm_k<<<g1, 256, 0, stream>>>(x, wg, lp);
    route_k<<<NBLK2, 1024, 0, stream>>>(lp, idxw, prob, rank, hist, gsum);
    scan_k<<<64, 512, 0, stream>>>(hist, offs, tot);
    finalize_k<<<1, 256, 0, stream>>>(tot, gsum, base, out);
    output_k<<<TE / 4 / 256, 256, 0, stream>>>(idxw, prob, rank, offs, base, out);
}